// Round 1
// baseline (231.256 us; speedup 1.0000x reference)
//
#include <hip/hip_runtime.h>

// Problem constants
#define B_ 32
#define N_ 4096
#define C_ 768
#define H_ 8
#define DH_ 96

// ws layout (floats):
//  q     [768]               @ 0
//  wqe   [H*C   = 6144]      @ 768
//  dots  [B*H*N = 1048576]   @ 8192          (softmax done in-place -> attn)
//  part  [16*B*H*C = 3145728]@ 8192+1048576
//  xbar  [B*H*C = 196608]
//  out1  [B*C   = 24576]
// total = 4,423,680 floats = 17.7 MB

// ---- q[e] = sum_c queries[c] * Wq[e,c] ------------------------------------
__global__ void k_q(const float* __restrict__ queries, const float* __restrict__ Wq,
                    float* __restrict__ q) {
  int e = blockIdx.x;
  int lane = threadIdx.x;           // 64 threads
  const float* row = Wq + (size_t)e * C_;
  float acc = 0.f;
#pragma unroll
  for (int p = 0; p < 3; ++p) {
    int c = p * 256 + lane * 4;
    float4 w = *(const float4*)(row + c);
    float4 qa = *(const float4*)(queries + c);
    acc += w.x * qa.x + w.y * qa.y + w.z * qa.z + w.w * qa.w;
  }
#pragma unroll
  for (int off = 32; off; off >>= 1) acc += __shfl_xor(acc, off);
  if (lane == 0) q[e] = acc;
}

// ---- wq_eff[h,c] = sum_d q[h*DH+d] * Wkv[h*DH+d, c] -----------------------
__global__ void k_wqeff(const float* __restrict__ q, const float* __restrict__ Wkv,
                        float* __restrict__ wqe) {
  int i = blockIdx.x * 256 + threadIdx.x;   // i < H*C
  int h = i / C_;
  int c = i - h * C_;
  const float* qh = q + h * DH_;
  float acc = 0.f;
  for (int d = 0; d < DH_; ++d)
    acc = fmaf(qh[d], Wkv[(size_t)(h * DH_ + d) * C_ + c], acc);
  wqe[i] = acc;
}

// ---- dots[b,h,n] = sum_c x[b,n,c] * wq_eff[h,c]  (pass 1 over x) ----------
__global__ __launch_bounds__(256) void k_dots(const float* __restrict__ x,
    const float* __restrict__ wqe, float* __restrict__ dots) {
  int lane = threadIdx.x & 63;
  int wgid = blockIdx.x * 4 + (threadIdx.x >> 6);
  // wq_eff held in registers: [3 c-passes][8 heads] float4 (96 VGPR)
  float4 wq[3][8];
#pragma unroll
  for (int p = 0; p < 3; ++p)
#pragma unroll
    for (int h = 0; h < H_; ++h)
      wq[p][h] = *(const float4*)(wqe + h * C_ + p * 256 + lane * 4);
  const int NW = 2048 * 4;                 // total waves in grid
  for (int row = wgid; row < B_ * N_; row += NW) {
    const float* xr = x + (size_t)row * C_;
    float acc[8] = {0.f,0.f,0.f,0.f,0.f,0.f,0.f,0.f};
#pragma unroll
    for (int p = 0; p < 3; ++p) {
      float4 xv = *(const float4*)(xr + p * 256 + lane * 4);
#pragma unroll
      for (int h = 0; h < H_; ++h) {
        acc[h] = fmaf(xv.x, wq[p][h].x, acc[h]);
        acc[h] = fmaf(xv.y, wq[p][h].y, acc[h]);
        acc[h] = fmaf(xv.z, wq[p][h].z, acc[h]);
        acc[h] = fmaf(xv.w, wq[p][h].w, acc[h]);
      }
    }
#pragma unroll
    for (int h = 0; h < H_; ++h)
#pragma unroll
      for (int off = 32; off; off >>= 1)
        acc[h] += __shfl_xor(acc[h], off);
    if (lane == 0) {
      int b = row >> 12, n = row & (N_ - 1);
      float* dp = dots + (size_t)b * H_ * N_ + n;
#pragma unroll
      for (int h = 0; h < H_; ++h) dp[(size_t)h * N_] = acc[h];
    }
  }
}

// ---- softmax over n, in place (one block per (b,h) row) -------------------
__global__ __launch_bounds__(256) void k_softmax(float* __restrict__ dots) {
  float* p = dots + (size_t)blockIdx.x * N_;
  int tid = threadIdx.x;
  float4 v[4];
  float m = -1e30f;
#pragma unroll
  for (int i = 0; i < 4; ++i) {
    v[i] = *(const float4*)(p + i * 1024 + tid * 4);
    m = fmaxf(m, fmaxf(fmaxf(v[i].x, v[i].y), fmaxf(v[i].z, v[i].w)));
  }
#pragma unroll
  for (int off = 32; off; off >>= 1) m = fmaxf(m, __shfl_xor(m, off));
  __shared__ float rmax[4], rsum[4];
  if ((tid & 63) == 0) rmax[tid >> 6] = m;
  __syncthreads();
  m = fmaxf(fmaxf(rmax[0], rmax[1]), fmaxf(rmax[2], rmax[3]));
  float s = 0.f;
#pragma unroll
  for (int i = 0; i < 4; ++i) {
    v[i].x = __expf(v[i].x - m); v[i].y = __expf(v[i].y - m);
    v[i].z = __expf(v[i].z - m); v[i].w = __expf(v[i].w - m);
    s += v[i].x + v[i].y + v[i].z + v[i].w;
  }
#pragma unroll
  for (int off = 32; off; off >>= 1) s += __shfl_xor(s, off);
  if ((tid & 63) == 0) rsum[tid >> 6] = s;
  __syncthreads();
  s = rsum[0] + rsum[1] + rsum[2] + rsum[3];
  float inv = 1.f / s;
#pragma unroll
  for (int i = 0; i < 4; ++i) {
    v[i].x *= inv; v[i].y *= inv; v[i].z *= inv; v[i].w *= inv;
    *(float4*)(p + i * 1024 + tid * 4) = v[i];
  }
}

// ---- partial xbar: per (b, n-chunk of 256): sum_n attn*x  (pass 2 over x) -
__global__ __launch_bounds__(192) void k_xpart(const float* __restrict__ x,
    const float* __restrict__ attn, float* __restrict__ part) {
  int ch = blockIdx.x;   // 0..15
  int b  = blockIdx.y;   // 0..31
  int tid = threadIdx.x; // 0..191, owns c = 4*tid..4*tid+3
  int n0 = ch * 256;
  __shared__ float satt[H_][256];
  for (int i = tid; i < H_ * 256; i += 192) {
    int h = i >> 8, n = i & 255;
    satt[h][n] = attn[((size_t)b * H_ + h) * N_ + n0 + n];
  }
  __syncthreads();
  float acc[H_][4];
#pragma unroll
  for (int h = 0; h < H_; ++h) { acc[h][0]=0.f; acc[h][1]=0.f; acc[h][2]=0.f; acc[h][3]=0.f; }
  const float* xp = x + ((size_t)b * N_ + n0) * C_ + tid * 4;
#pragma unroll 4
  for (int n = 0; n < 256; ++n) {
    float4 xv = *(const float4*)(xp + (size_t)n * C_);
#pragma unroll
    for (int h = 0; h < H_; ++h) {
      float a = satt[h][n];
      acc[h][0] = fmaf(a, xv.x, acc[h][0]);
      acc[h][1] = fmaf(a, xv.y, acc[h][1]);
      acc[h][2] = fmaf(a, xv.z, acc[h][2]);
      acc[h][3] = fmaf(a, xv.w, acc[h][3]);
    }
  }
  float* pp = part + ((size_t)ch * B_ + b) * H_ * C_ + tid * 4;
#pragma unroll
  for (int h = 0; h < H_; ++h)
    *(float4*)(pp + (size_t)h * C_) = make_float4(acc[h][0], acc[h][1], acc[h][2], acc[h][3]);
}

// ---- combine 16 chunk partials -> xbar ------------------------------------
__global__ void k_comb(const float* __restrict__ part, float* __restrict__ xbar) {
  int i = blockIdx.x * 256 + threadIdx.x;  // < B*H*C = 196608
  float s = 0.f;
#pragma unroll
  for (int ch = 0; ch < 16; ++ch) s += part[(size_t)ch * (B_ * H_ * C_) + i];
  xbar[i] = s;
}

// ---- out1[b,e] = sum_c xbar[b, e/DH, c] * Wkv[C+e, c] ---------------------
__global__ __launch_bounds__(256) void k_out1(const float* __restrict__ xbar,
    const float* __restrict__ Wkv, float* __restrict__ out1) {
  int b = blockIdx.y;
  int wv = threadIdx.x >> 6, lane = threadIdx.x & 63;
  int e0 = blockIdx.x * 64 + wv * 16;
  for (int it = 0; it < 16; ++it) {
    int e = e0 + it;
    int h = e / DH_;
    const float* wr = Wkv + (size_t)(C_ + e) * C_;
    const float* xr = xbar + ((size_t)b * H_ + h) * C_;
    float acc = 0.f;
#pragma unroll
    for (int p = 0; p < 3; ++p) {
      int c = p * 256 + lane * 4;
      float4 w = *(const float4*)(wr + c);
      float4 xv = *(const float4*)(xr + c);
      acc += w.x * xv.x + w.y * xv.y + w.z * xv.z + w.w * xv.w;
    }
#pragma unroll
    for (int off = 32; off; off >>= 1) acc += __shfl_xor(acc, off);
    if (lane == 0) out1[(size_t)b * C_ + e] = acc;
  }
}

// ---- y[b,e] = sum_c out1[b,c] * Wproj[e,c] + bproj[e] ---------------------
__global__ __launch_bounds__(256) void k_proj(const float* __restrict__ out1,
    const float* __restrict__ Wproj, const float* __restrict__ bproj,
    float* __restrict__ y) {
  int b = blockIdx.y;
  int wv = threadIdx.x >> 6, lane = threadIdx.x & 63;
  int e0 = blockIdx.x * 64 + wv * 16;
  const float* xr = out1 + (size_t)b * C_;
  for (int it = 0; it < 16; ++it) {
    int e = e0 + it;
    const float* wr = Wproj + (size_t)e * C_;
    float acc = 0.f;
#pragma unroll
    for (int p = 0; p < 3; ++p) {
      int c = p * 256 + lane * 4;
      float4 w = *(const float4*)(wr + c);
      float4 xv = *(const float4*)(xr + c);
      acc += w.x * xv.x + w.y * xv.y + w.z * xv.z + w.w * xv.w;
    }
#pragma unroll
    for (int off = 32; off; off >>= 1) acc += __shfl_xor(acc, off);
    if (lane == 0) y[(size_t)b * C_ + e] = acc + bproj[e];
  }
}

extern "C" void kernel_launch(void* const* d_in, const int* in_sizes, int n_in,
                              void* d_out, int out_size, void* d_ws, size_t ws_size,
                              hipStream_t stream) {
  const float* x       = (const float*)d_in[0];
  const float* queries = (const float*)d_in[1];
  const float* Wq      = (const float*)d_in[2];
  const float* Wkv     = (const float*)d_in[3];
  const float* Wproj   = (const float*)d_in[4];
  const float* bproj   = (const float*)d_in[5];
  float* y  = (float*)d_out;
  float* ws = (float*)d_ws;

  float* q    = ws;                                   // 768
  float* wqe  = ws + 768;                             // 6144
  float* dots = ws + 8192;                            // B*H*N
  float* part = dots + (size_t)B_ * H_ * N_;          // 16*B*H*C
  float* xbar = part + (size_t)16 * B_ * H_ * C_;     // B*H*C
  float* out1 = xbar + (size_t)B_ * H_ * C_;          // B*C

  hipLaunchKernelGGL(k_q,       dim3(C_),            dim3(64),  0, stream, queries, Wq, q);
  hipLaunchKernelGGL(k_wqeff,   dim3(H_ * C_ / 256), dim3(256), 0, stream, q, Wkv, wqe);
  hipLaunchKernelGGL(k_dots,    dim3(2048),          dim3(256), 0, stream, x, wqe, dots);
  hipLaunchKernelGGL(k_softmax, dim3(B_ * H_),       dim3(256), 0, stream, dots);
  hipLaunchKernelGGL(k_xpart,   dim3(16, B_),        dim3(192), 0, stream, x, dots, part);
  hipLaunchKernelGGL(k_comb,    dim3(B_ * H_ * C_ / 256), dim3(256), 0, stream, part, xbar);
  hipLaunchKernelGGL(k_out1,    dim3(12, B_),        dim3(256), 0, stream, xbar, Wkv, out1);
  hipLaunchKernelGGL(k_proj,    dim3(12, B_),        dim3(256), 0, stream, out1, Wproj, bproj, y);
}

// Round 2
// 207.437 us; speedup vs baseline: 1.1148x; 1.1148x over previous
//
#include <hip/hip_runtime.h>

// Problem constants
#define B_ 32
#define N_ 4096
#define C_ 768
#define H_ 8
#define DH_ 96
#define CHUNK 128
#define NCH (N_ / CHUNK)   // 32 chunks per batch row

struct F3 { float x, y, z; };   // 12B, align 4 -> dwordx3

// ws layout (floats):
//  q     [0, 768)
//  wqe   [1024, 7168)
//  mpart [8192, 16384)      (B*H*NCH = 8192)
//  spart [16384, 24576)
//  part  [24576, +6291456)  (NCH * B*H*C = 25 MB)
//  xbar  next 196608
//  out1  next 24576
// total ~= 26.2 MB

// ---- q[e] = sum_c queries[c] * Wq[e,c] ------------------------------------
__global__ void k_q(const float* __restrict__ queries, const float* __restrict__ Wq,
                    float* __restrict__ q) {
  int e = blockIdx.x;
  int lane = threadIdx.x;
  const float* row = Wq + (size_t)e * C_;
  float acc = 0.f;
#pragma unroll
  for (int p = 0; p < 3; ++p) {
    int c = p * 256 + lane * 4;
    float4 w = *(const float4*)(row + c);
    float4 qa = *(const float4*)(queries + c);
    acc += w.x * qa.x + w.y * qa.y + w.z * qa.z + w.w * qa.w;
  }
#pragma unroll
  for (int off = 32; off; off >>= 1) acc += __shfl_xor(acc, off);
  if (lane == 0) q[e] = acc;
}

// ---- wq_eff[h,c] = sum_d q[h*DH+d] * Wkv[h*DH+d, c] -----------------------
__global__ void k_wqeff(const float* __restrict__ q, const float* __restrict__ Wkv,
                        float* __restrict__ wqe) {
  int i = blockIdx.x * 256 + threadIdx.x;
  int h = i / C_;
  int c = i - h * C_;
  const float* qh = q + h * DH_;
  float acc = 0.f;
  for (int d = 0; d < DH_; ++d)
    acc = fmaf(qh[d], Wkv[(size_t)(h * DH_ + d) * C_ + c], acc);
  wqe[i] = acc;
}

// ---- fused: dots -> chunk softmax -> weighted x accumulation --------------
// grid (NCH, B_), block 256. Occupancy pinned ~3 blocks/CU via dynamic LDS pad.
__global__ __launch_bounds__(256, 3) void k_fused(const float* __restrict__ x,
    const float* __restrict__ wqe, float* __restrict__ part,
    float* __restrict__ mpart, float* __restrict__ spart) {
  extern __shared__ float g_dynpad[];   // occupancy control only
  (void)g_dynpad;
  __shared__ float sdp[H_ * CHUNK * 4]; // 16 KB: 4 lane-group partials per (h,row)
  __shared__ float sd[H_][CHUNK];       // 4 KB: att weights

  const int ch = blockIdx.x, b = blockIdx.y;
  const int tid = threadIdx.x, lane = tid & 63, wid = tid >> 6;
  const float* xb = x + ((size_t)b * N_ + (size_t)ch * CHUNK) * C_;

  // ---- Phase A: dots for 128 rows x 8 heads -------------------------------
  {
    float4 wq[3][H_];   // 96 VGPR, reused across all rows
#pragma unroll
    for (int p = 0; p < 3; ++p)
#pragma unroll
      for (int h = 0; h < H_; ++h)
        wq[p][h] = *(const float4*)(wqe + h * C_ + p * 256 + lane * 4);

    for (int r0 = wid * 2; r0 < CHUNK; r0 += 8) {   // 2 rows per iter per wave
      const float* x0 = xb + (size_t)r0 * C_;
      const float* x1 = x0 + C_;
      float4 xv0[3], xv1[3];
#pragma unroll
      for (int p = 0; p < 3; ++p) xv0[p] = *(const float4*)(x0 + p * 256 + lane * 4);
#pragma unroll
      for (int p = 0; p < 3; ++p) xv1[p] = *(const float4*)(x1 + p * 256 + lane * 4);
      float a0[H_], a1[H_];
#pragma unroll
      for (int h = 0; h < H_; ++h) { a0[h] = 0.f; a1[h] = 0.f; }
#pragma unroll
      for (int p = 0; p < 3; ++p) {
#pragma unroll
        for (int h = 0; h < H_; ++h) {
          a0[h] = fmaf(xv0[p].x, wq[p][h].x, a0[h]);
          a0[h] = fmaf(xv0[p].y, wq[p][h].y, a0[h]);
          a0[h] = fmaf(xv0[p].z, wq[p][h].z, a0[h]);
          a0[h] = fmaf(xv0[p].w, wq[p][h].w, a0[h]);
          a1[h] = fmaf(xv1[p].x, wq[p][h].x, a1[h]);
          a1[h] = fmaf(xv1[p].y, wq[p][h].y, a1[h]);
          a1[h] = fmaf(xv1[p].z, wq[p][h].z, a1[h]);
          a1[h] = fmaf(xv1[p].w, wq[p][h].w, a1[h]);
        }
      }
      // 4-level butterfly within 16-lane groups (DPP-friendly offsets)
#pragma unroll
      for (int h = 0; h < H_; ++h) {
#pragma unroll
        for (int off = 1; off <= 8; off <<= 1) {
          a0[h] += __shfl_xor(a0[h], off);
          a1[h] += __shfl_xor(a1[h], off);
        }
      }
      if ((lane & 15) == 0) {
        int g = lane >> 4;
#pragma unroll
        for (int h = 0; h < H_; ++h) {
          sdp[(h * CHUNK + r0) * 4 + g]     = a0[h];
          sdp[(h * CHUNK + r0 + 1) * 4 + g] = a1[h];
        }
      }
    }
  }
  __syncthreads();

  // ---- Phase B: chunk-local softmax (per head); write m,s partials --------
  {
#pragma unroll
    for (int hh = 0; hh < 2; ++hh) {
      int h = wid * 2 + hh;
      const float* pp = sdp + (size_t)h * CHUNK * 4;
      float4 p0 = *(const float4*)(pp + lane * 4);
      float4 p1 = *(const float4*)(pp + (lane + 64) * 4);
      float d0 = (p0.x + p0.y) + (p0.z + p0.w);
      float d1 = (p1.x + p1.y) + (p1.z + p1.w);
      float mx = fmaxf(d0, d1);
#pragma unroll
      for (int off = 32; off; off >>= 1) mx = fmaxf(mx, __shfl_xor(mx, off));
      float e0 = __expf(d0 - mx), e1 = __expf(d1 - mx);
      float s = e0 + e1;
#pragma unroll
      for (int off = 32; off; off >>= 1) s += __shfl_xor(s, off);
      sd[h][lane] = e0;
      sd[h][lane + 64] = e1;
      if (lane == 0) {
        mpart[((size_t)b * H_ + h) * NCH + ch] = mx;
        spart[((size_t)b * H_ + h) * NCH + ch] = s;
      }
    }
  }
  __syncthreads();

  // ---- Phase C: part[h][c] = sum_n att[h][n] * x[n][c]  (x re-read: L2/L3)
  {
    int c0 = tid * 3;                    // 256 threads x 3 floats = 768
    float acc[H_][3];
#pragma unroll
    for (int h = 0; h < H_; ++h) { acc[h][0] = 0.f; acc[h][1] = 0.f; acc[h][2] = 0.f; }
    const float* xc = xb + c0;
    for (int n4 = 0; n4 < CHUNK; n4 += 4) {
      float4 w[H_];
#pragma unroll
      for (int h = 0; h < H_; ++h) w[h] = *(const float4*)&sd[h][n4];   // broadcast
      F3 xv[4];
      const float* xr = xc + (size_t)n4 * C_;
#pragma unroll
      for (int k = 0; k < 4; ++k) xv[k] = *(const F3*)(xr + (size_t)k * C_);
#pragma unroll
      for (int k = 0; k < 4; ++k) {
#pragma unroll
        for (int h = 0; h < H_; ++h) {
          float aw = (k == 0) ? w[h].x : (k == 1) ? w[h].y : (k == 2) ? w[h].z : w[h].w;
          acc[h][0] = fmaf(aw, xv[k].x, acc[h][0]);
          acc[h][1] = fmaf(aw, xv[k].y, acc[h][1]);
          acc[h][2] = fmaf(aw, xv[k].z, acc[h][2]);
        }
      }
    }
    float* pp = part + ((size_t)(ch * B_ + b) * H_) * C_ + c0;
#pragma unroll
    for (int h = 0; h < H_; ++h) {
      F3 o = { acc[h][0], acc[h][1], acc[h][2] };
      *(F3*)(pp + (size_t)h * C_) = o;
    }
  }
}

// ---- combine chunk partials with LSE merge -> xbar ------------------------
__global__ __launch_bounds__(256) void k_comb2(const float* __restrict__ part,
    const float* __restrict__ mpart, const float* __restrict__ spart,
    float* __restrict__ xbar) {
  int i = blockIdx.x * 256 + threadIdx.x;     // < B*H*C
  int bh = i / C_;
  const float* m = mpart + (size_t)bh * NCH;
  const float* s = spart + (size_t)bh * NCH;
  float M = -1e30f;
#pragma unroll
  for (int ch = 0; ch < NCH; ++ch) M = fmaxf(M, m[ch]);
  float denom = 0.f, acc = 0.f;
#pragma unroll 4
  for (int ch = 0; ch < NCH; ++ch) {
    float w = __expf(m[ch] - M);
    denom += w * s[ch];
    acc = fmaf(w, part[(size_t)ch * (B_ * H_ * C_) + i], acc);
  }
  xbar[i] = acc / denom;
}

// ---- out1[b,e] = sum_c xbar[b, e/DH, c] * Wkv[C+e, c] ---------------------
__global__ __launch_bounds__(256) void k_out1(const float* __restrict__ xbar,
    const float* __restrict__ Wkv, float* __restrict__ out1) {
  int b = blockIdx.y;
  int wv = threadIdx.x >> 6, lane = threadIdx.x & 63;
  int e0 = blockIdx.x * 64 + wv * 16;
  for (int it = 0; it < 16; ++it) {
    int e = e0 + it;
    int h = e / DH_;
    const float* wr = Wkv + (size_t)(C_ + e) * C_;
    const float* xr = xbar + ((size_t)b * H_ + h) * C_;
    float acc = 0.f;
#pragma unroll
    for (int p = 0; p < 3; ++p) {
      int c = p * 256 + lane * 4;
      float4 w = *(const float4*)(wr + c);
      float4 xv = *(const float4*)(xr + c);
      acc += w.x * xv.x + w.y * xv.y + w.z * xv.z + w.w * xv.w;
    }
#pragma unroll
    for (int off = 32; off; off >>= 1) acc += __shfl_xor(acc, off);
    if (lane == 0) out1[(size_t)b * C_ + e] = acc;
  }
}

// ---- y[b,e] = sum_c out1[b,c] * Wproj[e,c] + bproj[e] ---------------------
__global__ __launch_bounds__(256) void k_proj(const float* __restrict__ out1,
    const float* __restrict__ Wproj, const float* __restrict__ bproj,
    float* __restrict__ y) {
  int b = blockIdx.y;
  int wv = threadIdx.x >> 6, lane = threadIdx.x & 63;
  int e0 = blockIdx.x * 64 + wv * 16;
  const float* xr = out1 + (size_t)b * C_;
  for (int it = 0; it < 16; ++it) {
    int e = e0 + it;
    const float* wr = Wproj + (size_t)e * C_;
    float acc = 0.f;
#pragma unroll
    for (int p = 0; p < 3; ++p) {
      int c = p * 256 + lane * 4;
      float4 w = *(const float4*)(wr + c);
      float4 xv = *(const float4*)(xr + c);
      acc += w.x * xv.x + w.y * xv.y + w.z * xv.z + w.w * xv.w;
    }
#pragma unroll
    for (int off = 32; off; off >>= 1) acc += __shfl_xor(acc, off);
    if (lane == 0) y[(size_t)b * C_ + e] = acc + bproj[e];
  }
}

extern "C" void kernel_launch(void* const* d_in, const int* in_sizes, int n_in,
                              void* d_out, int out_size, void* d_ws, size_t ws_size,
                              hipStream_t stream) {
  const float* x       = (const float*)d_in[0];
  const float* queries = (const float*)d_in[1];
  const float* Wq      = (const float*)d_in[2];
  const float* Wkv     = (const float*)d_in[3];
  const float* Wproj   = (const float*)d_in[4];
  const float* bproj   = (const float*)d_in[5];
  float* y  = (float*)d_out;
  float* ws = (float*)d_ws;

  float* q     = ws;                                  // 768
  float* wqe   = ws + 1024;                           // 6144
  float* mpart = ws + 8192;                           // 8192
  float* spart = ws + 16384;                          // 8192
  float* part  = ws + 24576;                          // NCH*B*H*C = 6291456
  float* xbar  = part + (size_t)NCH * B_ * H_ * C_;   // 196608
  float* out1  = xbar + (size_t)B_ * H_ * C_;         // 24576

  hipLaunchKernelGGL(k_q,     dim3(C_),            dim3(64),  0, stream, queries, Wq, q);
  hipLaunchKernelGGL(k_wqeff, dim3(H_ * C_ / 256), dim3(256), 0, stream, q, Wkv, wqe);
  // dynamic LDS pad: static 20 KB + 32 KB pad = 52 KB -> 3 blocks/CU
  hipLaunchKernelGGL(k_fused, dim3(NCH, B_),       dim3(256), 32768, stream,
                     x, wqe, part, mpart, spart);
  hipLaunchKernelGGL(k_comb2, dim3(B_ * H_ * C_ / 256), dim3(256), 0, stream,
                     part, mpart, spart, xbar);
  hipLaunchKernelGGL(k_out1,  dim3(12, B_),        dim3(256), 0, stream, xbar, Wkv, out1);
  hipLaunchKernelGGL(k_proj,  dim3(12, B_),        dim3(256), 0, stream, out1, Wproj, bproj, y);
}